// Round 17
// baseline (26.938 us; speedup 1.0000x reference)
//
#include <hip/hip_runtime.h>
#include <math.h>

#define F_LEN 21
#define D_LEN 41
#define S_LEN 61                 // F_LEN + D_LEN - 1
#define ROWS 8                   // rows per tile (= per wave)
#define TILES 4                  // tiles per block (pipeline depth 2 LDS bufs)
#define THREADS 64               // single-wave blocks: NO barriers anywhere
#define TFLO (ROWS * S_LEN)      // 488 floats per array per tile
#define TPAD 512                 // padded LDS floats per array per buffer
#define DOUTT (ROWS * D_LEN)     // 328 dist floats per tile
#define DV4T (DOUTT / 4)         // 82

// DPP add-reduce within 8-lane groups (VALU, no LDS pipe).
template <int CTRL>
__device__ __forceinline__ float dpp_add(float x) {
    int y = __builtin_amdgcn_update_dpp(0, __float_as_int(x), CTRL, 0xf, 0xf, true);
    return x + __int_as_float(y);
}
#define DPP_XOR1 0xB1            // quad_perm [1,0,3,2]
#define DPP_XOR2 0x4E            // quad_perm [2,3,0,1]
#define DPP_XOR7 0x141           // row_half_mirror: i -> i^7 within 8-group

__device__ __forceinline__ void gll16(const float* g, float* l) {
    __builtin_amdgcn_global_load_lds(
        (const __attribute__((address_space(1))) void*)g,
        (__attribute__((address_space(3))) void*)l, 16, 0, 0);
}

// One tile (488 floats per array) -> linear LDS. Exactly 4 gll ops:
// full 64-lane (floats 0..255) + 58-lane tail (floats 256..487), x2 arrays.
__device__ __forceinline__ void stage_tile(const float* pf_g, const float* pb_g,
                                           float* bufF, float* bufB,
                                           int row0, int lane) {
    const float* gf = pf_g + (size_t)row0 * S_LEN;
    const float* gb = pb_g + (size_t)row0 * S_LEN;
    gll16(gf + lane * 4, bufF);
    gll16(gb + lane * 4, bufB);
    if (lane < 58) {
        gll16(gf + 256 + lane * 4, bufF + 256);
        gll16(gb + 256 + lane * 4, bufB + 256);
    }
}

#define FENCE() do { asm volatile("" ::: "memory"); \
                     __builtin_amdgcn_sched_barrier(0); } while (0)

// Barrier-free counted-vmcnt pipeline: wave computes tile t from buf[t&1]
// while tile t+1's gll DMA is in flight. Tile-ready gate: total outstanding
// vmem <= 4  ==> (loads retire in order) the 4 outstanding can only be tile
// t+1's glls => tile t landed. Robust to store retirement order and spills
// (both only make the wait more conservative).
__global__ __launch_bounds__(THREADS, 4) void bp_kernel(
    const float* __restrict__ pf_g, const float* __restrict__ pb_g,
    const float* __restrict__ slop_g, const float* __restrict__ amp_g,
    float* __restrict__ out_dist, float* __restrict__ out_mean,
    float* __restrict__ out_ivar)
{
    __shared__ float ldsF[2][TPAD];
    __shared__ float ldsB[2][TPAD];
    __shared__ float distL[DOUTT];

    const int lane = threadIdx.x;
    const int rl   = lane >> 3;               // local row 0..7
    const int q    = lane & 7;                // octant within row
    const int brow = blockIdx.x * (TILES * ROWS);

    // ---- prologue: all per-tile scalars, then 2 tiles of gll DMA ---------
    float aT[TILES], sT[TILES];
    #pragma unroll
    for (int t = 0; t < TILES; ++t) {
        aT[t] = amp_g[brow + t * ROWS + rl];
        sT[t] = slop_g[brow + t * ROWS + rl];
    }
    FENCE();
    stage_tile(pf_g, pb_g, ldsF[0], ldsB[0], brow, lane);
    FENCE();
    stage_tile(pf_g, pb_g, ldsF[1], ldsB[1], brow + ROWS, lane);
    FENCE();

    const int  d0   = q * 5;
    const bool has6 = (q == 7);
    const int  base = rl * S_LEN + d0;

    #pragma unroll
    for (int t = 0; t < TILES; ++t) {
        // tile-t-ready gate (see header comment)
        if (t < TILES - 1) asm volatile("s_waitcnt vmcnt(4)" ::: "memory");
        else               asm volatile("s_waitcnt vmcnt(0)" ::: "memory");
        __builtin_amdgcn_sched_barrier(0);

        const int   r  = brow + t * ROWS + rl;
        const float a  = aT[t];
        const float sl = sT[t];

        // lf[21] via log-depth power tree (registers, no serial chain)
        float lf[F_LEN];
        lf[10] = 0.5f;
        {
            const float E1 = __expf(1.0f / sl);   // slop >= 0.5
            const float E2 = E1 * E1;
            const float E4 = E2 * E2;
            const float E8 = E4 * E4;
            float Ek[11];
            Ek[1] = E1;         Ek[2] = E2;       Ek[3] = E2 * E1;
            Ek[4] = E4;         Ek[5] = E4 * E1;  Ek[6] = E4 * E2;
            Ek[7] = E4 * Ek[3]; Ek[8] = E8;       Ek[9] = E8 * E1;
            Ek[10] = E8 * E2;
            #pragma unroll
            for (int k = 1; k <= 10; ++k) {
                float rcp = __frcp_rn(Ek[k] + 1.0f);
                float dl  = a * ((Ek[k] - 1.0f) * rcp);
                lf[10 + k] = 0.5f - dl;
                lf[10 - k] = 0.5f + dl;
            }
        }

        // column-streaming products from buf[t&1] (static buffer index)
        const float* Fb = ldsF[t & 1];
        const float* Bb = ldsB[t & 1];
        float prod[6] = {1.0f, 1.0f, 1.0f, 1.0f, 1.0f, 1.0f};
        #pragma unroll
        for (int i = 0; i < 26; ++i) {
            float fv = Fb[base + i];
            float bv = Bb[base + i];
            float df = fv - bv;
            #pragma unroll
            for (int dp = 0; dp < 6; ++dp) {
                const int j = i - dp;             // compile-time constant
                if (j >= 0 && j < F_LEN) {
                    float tm = fmaf(lf[j], df, bv);
                    if (dp == 5) tm = has6 ? tm : 1.0f;
                    prod[dp] *= tm;
                }
            }
        }

        // moments + 8-lane DPP butterfly
        const float df0 = (float)d0;
        float s0 = 0.0f, s1 = 0.0f, s2 = 0.0f;
        #pragma unroll
        for (int dp = 0; dp < 6; ++dp) {
            float p = prod[dp];
            if (dp == 5) p = has6 ? p : 0.0f;
            float dv = df0 + (float)dp;
            s0 += p;
            s1 += dv * p;
            s2 += dv * dv * p;
        }
        s0 = dpp_add<DPP_XOR1>(s0); s0 = dpp_add<DPP_XOR2>(s0); s0 = dpp_add<DPP_XOR7>(s0);
        s1 = dpp_add<DPP_XOR1>(s1); s1 = dpp_add<DPP_XOR2>(s1); s1 = dpp_add<DPP_XOR7>(s1);
        s2 = dpp_add<DPP_XOR1>(s2); s2 = dpp_add<DPP_XOR2>(s2); s2 = dpp_add<DPP_XOR7>(s2);

        const float inv      = 1.0f / fmaxf(s0, 1e-12f);
        const float mean_tmp = s1 * inv;
        const float m2       = s2 * inv;
        const float var_tmp  = fmaf(-mean_tmp, mean_tmp, m2);

        // buf[t&1] fully consumed (reads retired) -> prefetch tile t+2 into it
        asm volatile("s_waitcnt lgkmcnt(0)" ::: "memory");
        __builtin_amdgcn_sched_barrier(0);
        if (t + 2 < TILES)
            stage_tile(pf_g, pb_g, ldsF[t & 1], ldsB[t & 1],
                       brow + (t + 2) * ROWS, lane);
        FENCE();

        if (q == 0) {
            const float two_a = 2.0f * a;
            const float at    = 0.5f * __logf((1.0f + two_a) / (1.0f - two_a));
            const float min_v = fmaxf(0.5f / (at * at), sl);
            const float var   = fmaxf(var_tmp, min_v);
            out_mean[r] = mean_tmp - 20.0f;
            out_ivar[r] = 1.0f / var;
        }

        // dist: stage normalized values in LDS, flat float4 copy-out
        // (single-wave: DS pipe is in-order per wave -> no barrier needed)
        #pragma unroll
        for (int dp = 0; dp < 5; ++dp)
            distL[rl * D_LEN + d0 + dp] = prod[dp] * inv;
        if (has6)
            distL[rl * D_LEN + 40] = prod[5] * inv;

        const float4* ld4 = (const float4*)distL;
        float4* o4 = (float4*)(out_dist + (size_t)(brow + t * ROWS) * D_LEN);
        #pragma unroll
        for (int it = 0; it < 2; ++it) {
            int idx4 = it * THREADS + lane;       // 0..81
            if (idx4 < DV4T) o4[idx4] = ld4[idx4];
        }
    }
}

extern "C" void kernel_launch(void* const* d_in, const int* in_sizes, int n_in,
                              void* d_out, int out_size, void* d_ws, size_t ws_size,
                              hipStream_t stream) {
    // inputs: [0] lines_feature (unused), [1] pf, [2] pb, [3] slop, [4] amp
    const float* pf   = (const float*)d_in[1];
    const float* pb   = (const float*)d_in[2];
    const float* slop = (const float*)d_in[3];
    const float* amp  = (const float*)d_in[4];

    const int rows = in_sizes[3];              // B * L = 131072

    float* out_dist = (float*)d_out;
    float* out_mean = out_dist + (size_t)rows * D_LEN;
    float* out_ivar = out_mean + rows;

    const int blocks = rows / (ROWS * TILES);  // 4096
    bp_kernel<<<blocks, THREADS, 0, stream>>>(pf, pb, slop, amp,
                                              out_dist, out_mean, out_ivar);
}